// Round 9
// baseline (300.032 us; speedup 1.0000x reference)
//
#include <hip/hip_runtime.h>
#include <stdint.h>

#define BB   8192
#define DD   1024
#define EE   8
#define RHH  128
#define EHH  256
#define NE1  2048        // E*EH
#define KX   2112        // NE1 + 8 bias cols + 56 zero pad; %64==0 (33 K-tiles)

using f32x4  = __attribute__((ext_vector_type(4))) float;
using bf16x8 = __attribute__((ext_vector_type(8))) __bf16;

__device__ __forceinline__ unsigned short f2bf(float f) {
    union { float f; uint32_t u; } v; v.f = f;
    uint32_t u = v.u;
    uint32_t r = (u + 0x7FFFu + ((u >> 16) & 1u)) >> 16;
    return (unsigned short)r;
}
__device__ __forceinline__ float bf2f(unsigned short h) {
    union { uint32_t u; float f; } v; v.u = ((uint32_t)h) << 16;
    return v.f;
}

__device__ __forceinline__ void llds16(void* l, const void* g) {
    __builtin_amdgcn_global_load_lds(
        (const __attribute__((address_space(1))) uint32_t*)g,
        (__attribute__((address_space(3))) uint32_t*)l, 16, 0, 0);
}

__device__ __forceinline__ void rawbar() {
    asm volatile("" ::: "memory");
    __builtin_amdgcn_s_barrier();
    asm volatile("" ::: "memory");
}

template<int N> __device__ __forceinline__ void vmwait() {
    asm volatile("s_waitcnt vmcnt(%0)" :: "n"(N) : "memory");
}

#define MFMA16(a,b,c) __builtin_amdgcn_mfma_f32_16x16x32_bf16(a,b,c,0,0,0)

// ---------------- coalesced prep, 512-thread body (LDS-tiled transposes) ----------------
// pbid roles: [0,512) W1t ; [512,1024) W2t ; [1024,1056) rw1t ;
// [1056,1058) W2t bias cols ; [1058,1060) W2t zero-pad cols.  (1060 blocks total)
__device__ __forceinline__ void prep512(float (*T)[65], int pbid, int tid,
    const float* __restrict__ rw1, const float* __restrict__ ew1,
    const float* __restrict__ ew2, const float* __restrict__ eb2,
    unsigned short* __restrict__ rw1t, unsigned short* __restrict__ W1t,
    unsigned short* __restrict__ W2t)
{
    const int hl = tid & 63, gq = tid >> 6;    // gq 0..7
    if (pbid < 512) {            // W1t[n=e*256+h][k] = ew1[e][k][h]
        int e = pbid >> 6, kt = (pbid >> 2) & 15, ht = pbid & 3;
        const float* src = ew1 + ((size_t)e << 18);
#pragma unroll
        for (int i = 0; i < 8; ++i) {
            int kl = i * 8 + gq;
            T[kl][hl] = src[(size_t)(kt * 64 + kl) * 256 + ht * 64 + hl];
        }
        __syncthreads();
#pragma unroll
        for (int i = 0; i < 8; ++i) {
            int hl2 = i * 8 + gq;
            int n = e * 256 + ht * 64 + hl2;
            W1t[(size_t)n * 1024 + kt * 64 + hl] = f2bf(T[hl][hl2]);
        }
    } else if (pbid < 1024) {    // W2t[d][np] = ew2[np][d]
        int b2 = pbid - 512;
        int npt = b2 >> 4, dt = b2 & 15;
#pragma unroll
        for (int i = 0; i < 8; ++i) {
            int npl = i * 8 + gq;
            T[npl][hl] = ew2[(size_t)(npt * 64 + npl) * 1024 + dt * 64 + hl];
        }
        __syncthreads();
#pragma unroll
        for (int i = 0; i < 8; ++i) {
            int dl2 = i * 8 + gq;
            int d = dt * 64 + dl2;
            W2t[(size_t)d * KX + npt * 64 + hl] = f2bf(T[hl][dl2]);
        }
    } else if (pbid < 1056) {    // rw1t[h][d] = rw1[d][h]
        int b2 = pbid - 1024;
        int dt = b2 >> 1, ht = b2 & 1;
#pragma unroll
        for (int i = 0; i < 8; ++i) {
            int dl = i * 8 + gq;
            T[dl][hl] = rw1[(size_t)(dt * 64 + dl) * 128 + ht * 64 + hl];
        }
        __syncthreads();
#pragma unroll
        for (int i = 0; i < 8; ++i) {
            int hl2 = i * 8 + gq;
            int h = ht * 64 + hl2;
            rw1t[(size_t)h * 1024 + dt * 64 + hl] = f2bf(T[hl][hl2]);
        }
    } else if (pbid < 1058) {    // bias cols: W2t[d][2048+e] = eb2[e][d]
        int d = (pbid - 1056) * 512 + tid;
        unsigned short vv[8];
#pragma unroll
        for (int e = 0; e < 8; ++e) vv[e] = f2bf(eb2[(size_t)e * 1024 + d]);
        *(uint4*)&W2t[(size_t)d * KX + NE1] = *(const uint4*)vv;
    } else {                     // zero pad cols 2056..2111
        int d = (pbid - 1058) * 512 + tid;
        uint4 z = make_uint4(0, 0, 0, 0);
#pragma unroll
        for (int j = 0; j < 7; ++j)
            *(uint4*)&W2t[(size_t)d * KX + NE1 + 8 + j * 8] = z;
    }
}

// mega0 (512 thr): cvt_x [0,2048) ; Hb zero-pad [2048,2064) ; level-0 prep [2064,3124)
__global__ __launch_bounds__(512) void mega0(
    const float* __restrict__ x, unsigned short* __restrict__ xb,
    unsigned short* __restrict__ Hb,
    const float* __restrict__ rw1, const float* __restrict__ ew1,
    const float* __restrict__ ew2, const float* __restrict__ eb2,
    unsigned short* __restrict__ rw1t, unsigned short* __restrict__ W1t,
    unsigned short* __restrict__ W2t)
{
    __shared__ float T[64][65];
    const int bid = blockIdx.x, tid = threadIdx.x;
    if (bid < 2048) {
        size_t idx = (size_t)bid * 512 + tid;      // 1,048,576 threads * 8 elems
        const float* p = x + idx * 8;
        uint32_t w[4];
#pragma unroll
        for (int j = 0; j < 4; ++j)
            w[j] = (uint32_t)f2bf(p[2 * j]) | ((uint32_t)f2bf(p[2 * j + 1]) << 16);
        *(uint4*)(xb + idx * 8) = make_uint4(w[0], w[1], w[2], w[3]);
    } else if (bid < 2064) {
        int row = (bid - 2048) * 512 + tid;        // 8192 rows
        uint4 z = make_uint4(0, 0, 0, 0);
        unsigned short* p = Hb + (size_t)row * KX + NE1 + EE;
#pragma unroll
        for (int j = 0; j < 7; ++j)
            *(uint4*)(p + j * 8) = z;
    } else {
        prep512(T, bid - 2064, tid, rw1, ew1, ew2, eb2, rw1t, W1t, W2t);
    }
}

// fallback standalone prep (single-buffer path)
__global__ __launch_bounds__(512) void prep_lvl512(
    const float* __restrict__ rw1, const float* __restrict__ ew1,
    const float* __restrict__ ew2, const float* __restrict__ eb2,
    unsigned short* __restrict__ rw1t, unsigned short* __restrict__ W1t,
    unsigned short* __restrict__ W2t)
{
    __shared__ float T[64][65];
    prep512(T, blockIdx.x, threadIdx.x, rw1, ew1, ew2, eb2, rw1t, W1t, W2t);
}

// ---------------- router (blocks <128) + optional next-level prep (blocks >=128) ----------------
__global__ __launch_bounds__(512, 2) void router_prep(
    const unsigned short* __restrict__ xb, const unsigned short* __restrict__ rw1t,
    const float* __restrict__ rw2, const float* __restrict__ rb1,
    const float* __restrict__ rb2, float* __restrict__ wbuf,
    unsigned short* __restrict__ Hb,
    const float* __restrict__ rw1_n, const float* __restrict__ ew1_n,
    const float* __restrict__ ew2_n, const float* __restrict__ eb2_n,
    unsigned short* __restrict__ rw1t_n, unsigned short* __restrict__ W1t_n,
    unsigned short* __restrict__ W2t_n)
{
    __shared__ __align__(16) char SR[73728];
    const int bid = blockIdx.x;
    const int tid = threadIdx.x;

    if (bid >= 128) {
        prep512((float (*)[65])SR, bid - 128, tid, rw1_n, ew1_n, ew2_n, eb2_n,
                rw1t_n, W1t_n, W2t_n);
        return;
    }

    const int lane = tid & 63, wv = tid >> 6;
    const int g = wv >> 2, wq = wv & 3;
    const int l16 = lane & 15, lhi = lane >> 4;
    const long m0 = (long)bid * 64;

    const int r0 = tid >> 2, sl = tid & 3;
    const int sg = sl ^ ((r0 >> 1) & 3);

    const int xrow = (tid >> 2) & 63, xkg = tid >> 8;
    const char* xsrc = (const char*)xb + (m0 + xrow) * 2048 + xkg * 1024 + sg * 16;
    const char* wsrc = (const char*)rw1t + (long)r0 * 2048 + sg * 16;

    f32x4 acc[8];
    const f32x4 zero = {0.f, 0.f, 0.f, 0.f};
#pragma unroll
    for (int i = 0; i < 8; ++i) acc[i] = zero;

    auto stage = [&](int buf, int t) {
        char* base = SR + buf * 24576;
        llds16(base + tid * 16, xsrc + t * 64);
        llds16(base + 8192 + tid * 16, wsrc + t * 64);
        llds16(base + 16384 + tid * 16, wsrc + 1024 + t * 64);
    };

    stage(0, 0); stage(1, 1);

    const int swz = (l16 >> 1) & 3;
    const int aoff = g * 2048 + (wq * 16 + l16) * 32 + ((lhi ^ swz) << 3);
    const int boff = 4096 + g * 4096 + l16 * 32 + ((lhi ^ swz) << 3);

    int cb = 0, sb = 2;
    for (int t = 0; t < 16; ++t) {
        if (t < 15) vmwait<3>(); else vmwait<0>();
        rawbar();
        const unsigned short* bufp = (const unsigned short*)(SR + cb * 24576);
        bf16x8 aF = *(const bf16x8*)&bufp[aoff];
        bf16x8 bF[8];
#pragma unroll
        for (int ni = 0; ni < 8; ++ni)
            bF[ni] = *(const bf16x8*)&bufp[boff + ni * 512];
        if (t + 2 < 16) stage(sb, t + 2);
        __builtin_amdgcn_s_setprio(1);
#pragma unroll
        for (int ni = 0; ni < 8; ++ni)
            acc[ni] = MFMA16(aF, bF[ni], acc[ni]);
        __builtin_amdgcn_s_setprio(0);
        cb = (cb + 1 == 3) ? 0 : cb + 1;
        sb = (sb + 1 == 3) ? 0 : sb + 1;
    }

    rawbar();

    float* rhs = (float*)SR;                     // [64][132]
    float* lg  = (float*)(SR + 64 * 132 * 4);    // [64][9]

    if (g == 1) {
#pragma unroll
        for (int ni = 0; ni < 8; ++ni)
#pragma unroll
            for (int rr = 0; rr < 4; ++rr)
                rhs[(wq * 16 + lhi * 4 + rr) * 132 + ni * 16 + l16] = acc[ni][rr];
    }
    rawbar();
    if (g == 0) {
#pragma unroll
        for (int ni = 0; ni < 8; ++ni) {
            float bv = rb1[ni * 16 + l16];
#pragma unroll
            for (int rr = 0; rr < 4; ++rr) {
                int row = wq * 16 + lhi * 4 + rr, col = ni * 16 + l16;
                float v = acc[ni][rr] + rhs[row * 132 + col] + bv;
                rhs[row * 132 + col] = fmaxf(v, 0.f);
            }
        }
    }
    rawbar();

    {
        const int row = tid & 63, e = tid >> 6;
        float a2 = rb2[e];
        for (int h = 0; h < 128; ++h)
            a2 += rhs[row * 132 + h] * rw2[h * 8 + e];
        lg[row * 9 + e] = a2;
    }
    rawbar();

    if (tid < 64) {
        const int row = tid;
        float l[8], m = -1e30f;
#pragma unroll
        for (int e = 0; e < 8; ++e) { l[e] = lg[row * 9 + e]; m = fmaxf(m, l[e]); }
        float s = 0.f;
#pragma unroll
        for (int e = 0; e < 8; ++e) { l[e] = expf(l[e] - m); s += l[e]; }
        float inv = 1.f / s;
        const long gr = m0 + row;
#pragma unroll
        for (int e = 0; e < 8; ++e) {
            float w = l[e] * inv;
            wbuf[gr * 8 + e] = w;
            Hb[gr * KX + NE1 + e] = f2bf(w);
        }
    }
}

// ---------------- R4-exact deep-pipelined GEMM + XCD-aware 1-D block decode ----------------
// C[M,N] = A[M,K] * Bt[N,K]^T. BM=256, 512 thr = 8 waves. NBUF-deep LDS rotation,
// SD=NBUF-1, ONE barrier + ONE counted vmcnt per K-tile (never 0 mid-loop).
// Ordering load-bearing: ds_reads BEFORE stage group (R7 stage-first = -43%).
// Grid is 1-D 256 blocks; y = bid&7 (N-tile), x = bid>>3 — round-robin dispatch pins
// one B panel (~4MB) per XCD's L2 (both GEMMs have exactly 8 N-tiles).
// EPI 1: bf16(relu(acc+bias[n])*wrow[m][n>>8]); EPI 2: bf16(acc); EPI 3: f32(acc)
template<int BNv, int BKv, int NBUF, int WNv, int EPI>
__global__ __launch_bounds__(512, 2)
void gemmT(const unsigned short* __restrict__ A, const unsigned short* __restrict__ Bt,
           void* __restrict__ C, const float* __restrict__ bias,
           const float* __restrict__ wrow,
           int K, int lda, int ldb, int ldc)
{
    constexpr int KH  = BKv / 32;
    constexpr int WMv = 8 / WNv;
    constexpr int MR  = 256 / WMv;
    constexpr int NC  = BNv / WNv;
    constexpr int MI  = MR / 16;
    constexpr int NI  = NC / 16;
    constexpr int NCH = 16 / MI;
    constexpr int ALP = 2;
    constexpr int BLP = (BNv * 64) / 8192;
    constexpr int LPT = KH * (ALP + BLP);
    constexpr int SD  = NBUF - 1;
    constexpr int AKH = 256 * 32;
    constexpr int BKH = BNv * 32;

    __shared__ __align__(16) unsigned short As[NBUF * KH * AKH];
    __shared__ __align__(16) unsigned short Bs[NBUF * KH * BKH];

    const int tid = threadIdx.x;
    const int lane = tid & 63, wv = tid >> 6;
    const int wr = wv / WNv, wc = wv % WNv;
    const int l16 = lane & 15, lhi = lane >> 4;
    const int bid = blockIdx.x;
    const long bm0 = (long)(bid >> 3) * 256;
    const long bn0 = (long)(bid & 7) * BNv;

    const int r0 = tid >> 2, sl = tid & 3;
    const int sg = sl ^ ((r0 >> 1) & 3);

    const char* aSrc[ALP];
    const char* bSrc[BLP];
#pragma unroll
    for (int a = 0; a < ALP; ++a)
        aSrc[a] = (const char*)A + (bm0 + a * 128 + r0) * (long)lda * 2 + sg * 16;
#pragma unroll
    for (int b = 0; b < BLP; ++b)
        bSrc[b] = (const char*)Bt + (bn0 + b * 128 + r0) * (long)ldb * 2 + sg * 16;

    f32x4 acc[MI][NI];
    const f32x4 zero = {0.f, 0.f, 0.f, 0.f};
#pragma unroll
    for (int i = 0; i < MI; ++i)
#pragma unroll
        for (int j = 0; j < NI; ++j)
            acc[i][j] = zero;

    auto stage = [&](int buf, int t) {
        const int cbyte = t * (BKv * 2);
#pragma unroll
        for (int kh = 0; kh < KH; ++kh) {
            char* ad = (char*)As + ((buf * KH + kh) * AKH) * 2 + tid * 16;
            char* bd = (char*)Bs + ((buf * KH + kh) * BKH) * 2 + tid * 16;
#pragma unroll
            for (int a = 0; a < ALP; ++a)
                llds16(ad + a * 8192, aSrc[a] + cbyte + kh * 64);
#pragma unroll
            for (int b = 0; b < BLP; ++b)
                llds16(bd + b * 8192, bSrc[b] + cbyte + kh * 64);
        }
    };

    const int nt = K / BKv;
#pragma unroll
    for (int p = 0; p < SD; ++p) stage(p, p);

    const int swz = (l16 >> 1) & 3;
    const int aoff = (wr * MR + l16) * 32 + ((lhi ^ swz) << 3);
    const int boff = (wc * NC + l16) * 32 + ((lhi ^ swz) << 3);

    int cb = 0, sb = SD % NBUF;
    for (int t = 0; t < nt; ++t) {
        const int rem = nt - 1 - t;
        if (rem >= SD - 1) vmwait<LPT * (SD - 1)>();
        else if constexpr (SD >= 3) {
            if (rem == 1) vmwait<LPT>(); else vmwait<0>();
        } else vmwait<0>();
        rawbar();

        bf16x8 aF[KH][MI], bF[KH][NI];
#pragma unroll
        for (int kh = 0; kh < KH; ++kh) {
            const unsigned short* ap = &As[(cb * KH + kh) * AKH];
            const unsigned short* bp = &Bs[(cb * KH + kh) * BKH];
#pragma unroll
            for (int mi = 0; mi < MI; ++mi)
                aF[kh][mi] = *(const bf16x8*)&ap[aoff + mi * 512];
#pragma unroll
            for (int ni = 0; ni < NI; ++ni)
                bF[kh][ni] = *(const bf16x8*)&bp[boff + ni * 512];
        }

        if (t + SD < nt) stage(sb, t + SD);   // stage AFTER reads (R4 ordering)

#pragma unroll
        for (int kh = 0; kh < KH; ++kh) {
#pragma unroll
            for (int nc0 = 0; nc0 < NI; nc0 += NCH) {
                __builtin_amdgcn_s_setprio(1);
#pragma unroll
                for (int mi = 0; mi < MI; ++mi)
#pragma unroll
                    for (int nj = 0; nj < NCH; ++nj)
                        acc[mi][nc0 + nj] = MFMA16(aF[kh][mi], bF[kh][nc0 + nj],
                                                   acc[mi][nc0 + nj]);
                __builtin_amdgcn_s_setprio(0);
            }
        }

        cb = (cb + 1 == NBUF) ? 0 : cb + 1;
        sb = (sb + 1 == NBUF) ? 0 : sb + 1;
    }

    // epilogue
#pragma unroll
    for (int mi = 0; mi < MI; ++mi) {
#pragma unroll
        for (int ni = 0; ni < NI; ++ni) {
            const long gn = bn0 + wc * NC + ni * 16 + l16;
            float bv = 0.f;
            if (EPI == 1) bv = bias[gn];
#pragma unroll
            for (int rr = 0; rr < 4; ++rr) {
                const long gm = bm0 + wr * MR + mi * 16 + lhi * 4 + rr;
                float v = acc[mi][ni][rr];
                if (EPI == 1) {
                    v = fmaxf(v + bv, 0.f) * wrow[gm * 8 + (int)(gn >> 8)];
                    ((unsigned short*)C)[gm * (long)ldc + gn] = f2bf(v);
                } else if (EPI == 2) {
                    ((unsigned short*)C)[gm * (long)ldc + gn] = f2bf(v);
                } else {
                    ((float*)C)[gm * (long)ldc + gn] = v;
                }
            }
        }
    }
}

// ---------------- launch ----------------

extern "C" void kernel_launch(void* const* d_in, const int* in_sizes, int n_in,
                              void* d_out, int out_size, void* d_ws, size_t ws_size,
                              hipStream_t stream) {
    (void)in_sizes; (void)n_in; (void)out_size;
    const float* x   = (const float*)d_in[0];
    const float* rw1 = (const float*)d_in[1];
    const float* rb1 = (const float*)d_in[2];
    const float* rw2 = (const float*)d_in[3];
    const float* rb2 = (const float*)d_in[4];
    const float* ew1 = (const float*)d_in[5];
    const float* eb1 = (const float*)d_in[6];
    const float* ew2 = (const float*)d_in[7];
    const float* eb2 = (const float*)d_in[8];

    const bool dbuf = ws_size >= 69206016u;   // double-buffered weights (prep overlap)

    char* ws = (char*)d_ws;
    unsigned short* xb   = (unsigned short*)(ws);                 // 16,777,216 B
    float*          wbuf = (float*)         (ws + 16777216);      //    262,144 B
    unsigned short* Hb   = (unsigned short*)(ws + 17039360);      // 34,603,008 B
    size_t off = 51642368;
    unsigned short* rw1tb[2];
    unsigned short* W1tb[2];
    unsigned short* W2tb[2];
    rw1tb[0] = (unsigned short*)(ws + off);
    rw1tb[1] = dbuf ? (unsigned short*)(ws + off + 262144) : rw1tb[0];
    off += (dbuf ? 2u : 1u) * 262144u;
    W1tb[0] = (unsigned short*)(ws + off);
    W1tb[1] = dbuf ? (unsigned short*)(ws + off + 4194304) : W1tb[0];
    off += (dbuf ? 2u : 1u) * 4194304u;
    W2tb[0] = (unsigned short*)(ws + off);
    W2tb[1] = dbuf ? (unsigned short*)(ws + off + 4325376) : W2tb[0];

    mega0<<<3124, 512, 0, stream>>>(x, xb, Hb, rw1, ew1, ew2, eb2,
                                    rw1tb[0], W1tb[0], W2tb[0]);

    for (int l = 0; l < 3; ++l) {
        const int b  = dbuf ? (l & 1) : 0;
        const int nb = dbuf ? (b ^ 1) : 0;
        const int ln = (l + 1 < 3) ? (l + 1) : 0;   // next-level srcs (unused when grid=128)

        if (!dbuf && l > 0)
            prep_lvl512<<<1060, 512, 0, stream>>>(rw1 + (size_t)l * DD * RHH,
                                                  ew1 + (size_t)l * EE * DD * EHH,
                                                  ew2 + (size_t)l * EE * EHH * DD,
                                                  eb2 + (size_t)l * EE * DD,
                                                  rw1tb[0], W1tb[0], W2tb[0]);

        const int rp_grid = (dbuf && l < 2) ? 1188 : 128;
        router_prep<<<rp_grid, 512, 0, stream>>>(
            xb, rw1tb[b],
            rw2 + (size_t)l * RHH * EE, rb1 + (size_t)l * RHH, rb2 + (size_t)l * EE,
            wbuf, Hb,
            rw1 + (size_t)ln * DD * RHH, ew1 + (size_t)ln * EE * DD * EHH,
            ew2 + (size_t)ln * EE * EHH * DD, eb2 + (size_t)ln * EE * DD,
            rw1tb[nb], W1tb[nb], W2tb[nb]);

        // H' = relu(x @ W1 + b1) * w   [8192, 2048] (stride KX)
        gemmT<256, 32, 4, 4, 1><<<256, 512, 0, stream>>>(
            xb, W1tb[b], Hb, eb1 + (size_t)l * NE1, wbuf, DD, DD, DD, KX);

        // out = H' @ W2ext (bias folded via K-extension)
        if (l < 2)
            gemmT<128, 64, 3, 2, 2><<<256, 512, 0, stream>>>(
                Hb, W2tb[b], xb, nullptr, nullptr, KX, KX, KX, DD);
        else
            gemmT<128, 64, 3, 2, 3><<<256, 512, 0, stream>>>(
                Hb, W2tb[b], d_out, nullptr, nullptr, KX, KX, KX, DD);
    }
}

// Round 10
// 272.968 us; speedup vs baseline: 1.0991x; 1.0991x over previous
//
#include <hip/hip_runtime.h>
#include <stdint.h>

#define BB   8192
#define DD   1024
#define EE   8
#define RHH  128
#define EHH  256
#define NE1  2048        // E*EH
#define KX   2112        // NE1 + 8 bias cols + 56 zero pad; %64==0 (33 K-tiles)

using f32x4  = __attribute__((ext_vector_type(4))) float;
using bf16x8 = __attribute__((ext_vector_type(8))) __bf16;

__device__ __forceinline__ unsigned short f2bf(float f) {
    union { float f; uint32_t u; } v; v.f = f;
    uint32_t u = v.u;
    uint32_t r = (u + 0x7FFFu + ((u >> 16) & 1u)) >> 16;
    return (unsigned short)r;
}
__device__ __forceinline__ float bf2f(unsigned short h) {
    union { uint32_t u; float f; } v; v.u = ((uint32_t)h) << 16;
    return v.f;
}

__device__ __forceinline__ void llds16(void* l, const void* g) {
    __builtin_amdgcn_global_load_lds(
        (const __attribute__((address_space(1))) uint32_t*)g,
        (__attribute__((address_space(3))) uint32_t*)l, 16, 0, 0);
}

__device__ __forceinline__ void rawbar() {
    asm volatile("" ::: "memory");
    __builtin_amdgcn_s_barrier();
    asm volatile("" ::: "memory");
}

template<int N> __device__ __forceinline__ void vmwait() {
    asm volatile("s_waitcnt vmcnt(%0)" :: "n"(N) : "memory");
}

#define MFMA16(a,b,c) __builtin_amdgcn_mfma_f32_16x16x32_bf16(a,b,c,0,0,0)

// ---------------- coalesced prep, 512-thread body (LDS-tiled transposes) ----------------
// pbid roles: [0,512) W1t ; [512,1024) W2t ; [1024,1056) rw1t ;
// [1056,1058) W2t bias cols ; [1058,1060) W2t zero-pad cols.  (1060 blocks total)
__device__ __forceinline__ void prep512(float (*T)[65], int pbid, int tid,
    const float* __restrict__ rw1, const float* __restrict__ ew1,
    const float* __restrict__ ew2, const float* __restrict__ eb2,
    unsigned short* __restrict__ rw1t, unsigned short* __restrict__ W1t,
    unsigned short* __restrict__ W2t)
{
    const int hl = tid & 63, gq = tid >> 6;    // gq 0..7
    if (pbid < 512) {            // W1t[n=e*256+h][k] = ew1[e][k][h]
        int e = pbid >> 6, kt = (pbid >> 2) & 15, ht = pbid & 3;
        const float* src = ew1 + ((size_t)e << 18);
#pragma unroll
        for (int i = 0; i < 8; ++i) {
            int kl = i * 8 + gq;
            T[kl][hl] = src[(size_t)(kt * 64 + kl) * 256 + ht * 64 + hl];
        }
        __syncthreads();
#pragma unroll
        for (int i = 0; i < 8; ++i) {
            int hl2 = i * 8 + gq;
            int n = e * 256 + ht * 64 + hl2;
            W1t[(size_t)n * 1024 + kt * 64 + hl] = f2bf(T[hl][hl2]);
        }
    } else if (pbid < 1024) {    // W2t[d][np] = ew2[np][d]
        int b2 = pbid - 512;
        int npt = b2 >> 4, dt = b2 & 15;
#pragma unroll
        for (int i = 0; i < 8; ++i) {
            int npl = i * 8 + gq;
            T[npl][hl] = ew2[(size_t)(npt * 64 + npl) * 1024 + dt * 64 + hl];
        }
        __syncthreads();
#pragma unroll
        for (int i = 0; i < 8; ++i) {
            int dl2 = i * 8 + gq;
            int d = dt * 64 + dl2;
            W2t[(size_t)d * KX + npt * 64 + hl] = f2bf(T[hl][dl2]);
        }
    } else if (pbid < 1056) {    // rw1t[h][d] = rw1[d][h]
        int b2 = pbid - 1024;
        int dt = b2 >> 1, ht = b2 & 1;
#pragma unroll
        for (int i = 0; i < 8; ++i) {
            int dl = i * 8 + gq;
            T[dl][hl] = rw1[(size_t)(dt * 64 + dl) * 128 + ht * 64 + hl];
        }
        __syncthreads();
#pragma unroll
        for (int i = 0; i < 8; ++i) {
            int hl2 = i * 8 + gq;
            int h = ht * 64 + hl2;
            rw1t[(size_t)h * 1024 + dt * 64 + hl] = f2bf(T[hl][hl2]);
        }
    } else if (pbid < 1058) {    // bias cols: W2t[d][2048+e] = eb2[e][d]
        int d = (pbid - 1056) * 512 + tid;
        unsigned short vv[8];
#pragma unroll
        for (int e = 0; e < 8; ++e) vv[e] = f2bf(eb2[(size_t)e * 1024 + d]);
        *(uint4*)&W2t[(size_t)d * KX + NE1] = *(const uint4*)vv;
    } else {                     // zero pad cols 2056..2111
        int d = (pbid - 1058) * 512 + tid;
        uint4 z = make_uint4(0, 0, 0, 0);
#pragma unroll
        for (int j = 0; j < 7; ++j)
            *(uint4*)&W2t[(size_t)d * KX + NE1 + 8 + j * 8] = z;
    }
}

// mega0 (512 thr): cvt_x [0,2048) ; Hb zero-pad [2048,2064) ; level-0 prep [2064,3124)
__global__ __launch_bounds__(512) void mega0(
    const float* __restrict__ x, unsigned short* __restrict__ xb,
    unsigned short* __restrict__ Hb,
    const float* __restrict__ rw1, const float* __restrict__ ew1,
    const float* __restrict__ ew2, const float* __restrict__ eb2,
    unsigned short* __restrict__ rw1t, unsigned short* __restrict__ W1t,
    unsigned short* __restrict__ W2t)
{
    __shared__ float T[64][65];
    const int bid = blockIdx.x, tid = threadIdx.x;
    if (bid < 2048) {
        size_t idx = (size_t)bid * 512 + tid;      // 1,048,576 threads * 8 elems
        const float* p = x + idx * 8;
        uint32_t w[4];
#pragma unroll
        for (int j = 0; j < 4; ++j)
            w[j] = (uint32_t)f2bf(p[2 * j]) | ((uint32_t)f2bf(p[2 * j + 1]) << 16);
        *(uint4*)(xb + idx * 8) = make_uint4(w[0], w[1], w[2], w[3]);
    } else if (bid < 2064) {
        int row = (bid - 2048) * 512 + tid;        // 8192 rows
        uint4 z = make_uint4(0, 0, 0, 0);
        unsigned short* p = Hb + (size_t)row * KX + NE1 + EE;
#pragma unroll
        for (int j = 0; j < 7; ++j)
            *(uint4*)(p + j * 8) = z;
    } else {
        prep512(T, bid - 2064, tid, rw1, ew1, ew2, eb2, rw1t, W1t, W2t);
    }
}

// fallback standalone prep (single-buffer path)
__global__ __launch_bounds__(512) void prep_lvl512(
    const float* __restrict__ rw1, const float* __restrict__ ew1,
    const float* __restrict__ ew2, const float* __restrict__ eb2,
    unsigned short* __restrict__ rw1t, unsigned short* __restrict__ W1t,
    unsigned short* __restrict__ W2t)
{
    __shared__ float T[64][65];
    prep512(T, blockIdx.x, threadIdx.x, rw1, ew1, ew2, eb2, rw1t, W1t, W2t);
}

// ---------------- router (blocks <128) + optional next-level prep (blocks >=128) ----------------
__global__ __launch_bounds__(512, 2) void router_prep(
    const unsigned short* __restrict__ xb, const unsigned short* __restrict__ rw1t,
    const float* __restrict__ rw2, const float* __restrict__ rb1,
    const float* __restrict__ rb2, float* __restrict__ wbuf,
    unsigned short* __restrict__ Hb,
    const float* __restrict__ rw1_n, const float* __restrict__ ew1_n,
    const float* __restrict__ ew2_n, const float* __restrict__ eb2_n,
    unsigned short* __restrict__ rw1t_n, unsigned short* __restrict__ W1t_n,
    unsigned short* __restrict__ W2t_n)
{
    __shared__ __align__(16) char SR[73728];
    const int bid = blockIdx.x;
    const int tid = threadIdx.x;

    if (bid >= 128) {
        prep512((float (*)[65])SR, bid - 128, tid, rw1_n, ew1_n, ew2_n, eb2_n,
                rw1t_n, W1t_n, W2t_n);
        return;
    }

    const int lane = tid & 63, wv = tid >> 6;
    const int g = wv >> 2, wq = wv & 3;
    const int l16 = lane & 15, lhi = lane >> 4;
    const long m0 = (long)bid * 64;

    const int r0 = tid >> 2, sl = tid & 3;
    const int sg = sl ^ ((r0 >> 1) & 3);

    const int xrow = (tid >> 2) & 63, xkg = tid >> 8;
    const char* xsrc = (const char*)xb + (m0 + xrow) * 2048 + xkg * 1024 + sg * 16;
    const char* wsrc = (const char*)rw1t + (long)r0 * 2048 + sg * 16;

    f32x4 acc[8];
    const f32x4 zero = {0.f, 0.f, 0.f, 0.f};
#pragma unroll
    for (int i = 0; i < 8; ++i) acc[i] = zero;

    auto stage = [&](int buf, int t) {
        char* base = SR + buf * 24576;
        llds16(base + tid * 16, xsrc + t * 64);
        llds16(base + 8192 + tid * 16, wsrc + t * 64);
        llds16(base + 16384 + tid * 16, wsrc + 1024 + t * 64);
    };

    stage(0, 0); stage(1, 1);

    const int swz = (l16 >> 1) & 3;
    const int aoff = g * 2048 + (wq * 16 + l16) * 32 + ((lhi ^ swz) << 3);
    const int boff = 4096 + g * 4096 + l16 * 32 + ((lhi ^ swz) << 3);

    int cb = 0, sb = 2;
    for (int t = 0; t < 16; ++t) {
        if (t < 15) vmwait<3>(); else vmwait<0>();
        rawbar();
        const unsigned short* bufp = (const unsigned short*)(SR + cb * 24576);
        bf16x8 aF = *(const bf16x8*)&bufp[aoff];
        bf16x8 bF[8];
#pragma unroll
        for (int ni = 0; ni < 8; ++ni)
            bF[ni] = *(const bf16x8*)&bufp[boff + ni * 512];
        if (t + 2 < 16) stage(sb, t + 2);
        __builtin_amdgcn_s_setprio(1);
#pragma unroll
        for (int ni = 0; ni < 8; ++ni)
            acc[ni] = MFMA16(aF, bF[ni], acc[ni]);
        __builtin_amdgcn_s_setprio(0);
        cb = (cb + 1 == 3) ? 0 : cb + 1;
        sb = (sb + 1 == 3) ? 0 : sb + 1;
    }

    rawbar();

    float* rhs = (float*)SR;                     // [64][132]
    float* lg  = (float*)(SR + 64 * 132 * 4);    // [64][9]

    if (g == 1) {
#pragma unroll
        for (int ni = 0; ni < 8; ++ni)
#pragma unroll
            for (int rr = 0; rr < 4; ++rr)
                rhs[(wq * 16 + lhi * 4 + rr) * 132 + ni * 16 + l16] = acc[ni][rr];
    }
    rawbar();
    if (g == 0) {
#pragma unroll
        for (int ni = 0; ni < 8; ++ni) {
            float bv = rb1[ni * 16 + l16];
#pragma unroll
            for (int rr = 0; rr < 4; ++rr) {
                int row = wq * 16 + lhi * 4 + rr, col = ni * 16 + l16;
                float v = acc[ni][rr] + rhs[row * 132 + col] + bv;
                rhs[row * 132 + col] = fmaxf(v, 0.f);
            }
        }
    }
    rawbar();

    {
        const int row = tid & 63, e = tid >> 6;
        float a2 = rb2[e];
        for (int h = 0; h < 128; ++h)
            a2 += rhs[row * 132 + h] * rw2[h * 8 + e];
        lg[row * 9 + e] = a2;
    }
    rawbar();

    if (tid < 64) {
        const int row = tid;
        float l[8], m = -1e30f;
#pragma unroll
        for (int e = 0; e < 8; ++e) { l[e] = lg[row * 9 + e]; m = fmaxf(m, l[e]); }
        float s = 0.f;
#pragma unroll
        for (int e = 0; e < 8; ++e) { l[e] = expf(l[e] - m); s += l[e]; }
        float inv = 1.f / s;
        const long gr = m0 + row;
#pragma unroll
        for (int e = 0; e < 8; ++e) {
            float w = l[e] * inv;
            wbuf[gr * 8 + e] = w;
            Hb[gr * KX + NE1 + e] = f2bf(w);
        }
    }
}

// ---------------- R8-exact deep-pipelined GEMM (2-D grid; no XCD remap) ----------------
// C[M,N] = A[M,K] * Bt[N,K]^T. BM=256, 512 thr = 8 waves. NBUF-deep LDS rotation,
// SD=NBUF-1, ONE barrier + ONE counted vmcnt per K-tile (never 0 mid-loop).
// Ordering load-bearing: ds_reads BEFORE stage group (R7 stage-first = -43%).
// Grid dim3(32,8): implicit XCD mapping (x%8) gives each XCD 4 A-tiles (8x reused);
// R9's y=bid&7 remap streamed FULL A per XCD -> FETCH 33.8->137 MB, +28 us. Reverted.
// EPI 1: bf16(relu(acc+bias[n])*wrow[m][n>>8]); EPI 2: bf16(acc); EPI 3: f32(acc)
template<int BNv, int BKv, int NBUF, int WNv, int EPI>
__global__ __launch_bounds__(512, 2)
void gemmT(const unsigned short* __restrict__ A, const unsigned short* __restrict__ Bt,
           void* __restrict__ C, const float* __restrict__ bias,
           const float* __restrict__ wrow,
           int K, int lda, int ldb, int ldc)
{
    constexpr int KH  = BKv / 32;
    constexpr int WMv = 8 / WNv;
    constexpr int MR  = 256 / WMv;
    constexpr int NC  = BNv / WNv;
    constexpr int MI  = MR / 16;
    constexpr int NI  = NC / 16;
    constexpr int NCH = 16 / MI;
    constexpr int ALP = 2;
    constexpr int BLP = (BNv * 64) / 8192;
    constexpr int LPT = KH * (ALP + BLP);
    constexpr int SD  = NBUF - 1;
    constexpr int AKH = 256 * 32;
    constexpr int BKH = BNv * 32;

    __shared__ __align__(16) unsigned short As[NBUF * KH * AKH];
    __shared__ __align__(16) unsigned short Bs[NBUF * KH * BKH];

    const int tid = threadIdx.x;
    const int lane = tid & 63, wv = tid >> 6;
    const int wr = wv / WNv, wc = wv % WNv;
    const int l16 = lane & 15, lhi = lane >> 4;
    const long bm0 = (long)blockIdx.x * 256;
    const long bn0 = (long)blockIdx.y * BNv;

    const int r0 = tid >> 2, sl = tid & 3;
    const int sg = sl ^ ((r0 >> 1) & 3);

    const char* aSrc[ALP];
    const char* bSrc[BLP];
#pragma unroll
    for (int a = 0; a < ALP; ++a)
        aSrc[a] = (const char*)A + (bm0 + a * 128 + r0) * (long)lda * 2 + sg * 16;
#pragma unroll
    for (int b = 0; b < BLP; ++b)
        bSrc[b] = (const char*)Bt + (bn0 + b * 128 + r0) * (long)ldb * 2 + sg * 16;

    f32x4 acc[MI][NI];
    const f32x4 zero = {0.f, 0.f, 0.f, 0.f};
#pragma unroll
    for (int i = 0; i < MI; ++i)
#pragma unroll
        for (int j = 0; j < NI; ++j)
            acc[i][j] = zero;

    auto stage = [&](int buf, int t) {
        const int cbyte = t * (BKv * 2);
#pragma unroll
        for (int kh = 0; kh < KH; ++kh) {
            char* ad = (char*)As + ((buf * KH + kh) * AKH) * 2 + tid * 16;
            char* bd = (char*)Bs + ((buf * KH + kh) * BKH) * 2 + tid * 16;
#pragma unroll
            for (int a = 0; a < ALP; ++a)
                llds16(ad + a * 8192, aSrc[a] + cbyte + kh * 64);
#pragma unroll
            for (int b = 0; b < BLP; ++b)
                llds16(bd + b * 8192, bSrc[b] + cbyte + kh * 64);
        }
    };

    const int nt = K / BKv;
#pragma unroll
    for (int p = 0; p < SD; ++p) stage(p, p);

    const int swz = (l16 >> 1) & 3;
    const int aoff = (wr * MR + l16) * 32 + ((lhi ^ swz) << 3);
    const int boff = (wc * NC + l16) * 32 + ((lhi ^ swz) << 3);

    int cb = 0, sb = SD % NBUF;
    for (int t = 0; t < nt; ++t) {
        const int rem = nt - 1 - t;
        if (rem >= SD - 1) vmwait<LPT * (SD - 1)>();
        else if constexpr (SD >= 3) {
            if (rem == 1) vmwait<LPT>(); else vmwait<0>();
        } else vmwait<0>();
        rawbar();

        bf16x8 aF[KH][MI], bF[KH][NI];
#pragma unroll
        for (int kh = 0; kh < KH; ++kh) {
            const unsigned short* ap = &As[(cb * KH + kh) * AKH];
            const unsigned short* bp = &Bs[(cb * KH + kh) * BKH];
#pragma unroll
            for (int mi = 0; mi < MI; ++mi)
                aF[kh][mi] = *(const bf16x8*)&ap[aoff + mi * 512];
#pragma unroll
            for (int ni = 0; ni < NI; ++ni)
                bF[kh][ni] = *(const bf16x8*)&bp[boff + ni * 512];
        }

        if (t + SD < nt) stage(sb, t + SD);   // stage AFTER reads (R4 ordering)

#pragma unroll
        for (int kh = 0; kh < KH; ++kh) {
#pragma unroll
            for (int nc0 = 0; nc0 < NI; nc0 += NCH) {
                __builtin_amdgcn_s_setprio(1);
#pragma unroll
                for (int mi = 0; mi < MI; ++mi)
#pragma unroll
                    for (int nj = 0; nj < NCH; ++nj)
                        acc[mi][nc0 + nj] = MFMA16(aF[kh][mi], bF[kh][nc0 + nj],
                                                   acc[mi][nc0 + nj]);
                __builtin_amdgcn_s_setprio(0);
            }
        }

        cb = (cb + 1 == NBUF) ? 0 : cb + 1;
        sb = (sb + 1 == NBUF) ? 0 : sb + 1;
    }

    // epilogue
#pragma unroll
    for (int mi = 0; mi < MI; ++mi) {
#pragma unroll
        for (int ni = 0; ni < NI; ++ni) {
            const long gn = bn0 + wc * NC + ni * 16 + l16;
            float bv = 0.f;
            if (EPI == 1) bv = bias[gn];
#pragma unroll
            for (int rr = 0; rr < 4; ++rr) {
                const long gm = bm0 + wr * MR + mi * 16 + lhi * 4 + rr;
                float v = acc[mi][ni][rr];
                if (EPI == 1) {
                    v = fmaxf(v + bv, 0.f) * wrow[gm * 8 + (int)(gn >> 8)];
                    ((unsigned short*)C)[gm * (long)ldc + gn] = f2bf(v);
                } else if (EPI == 2) {
                    ((unsigned short*)C)[gm * (long)ldc + gn] = f2bf(v);
                } else {
                    ((float*)C)[gm * (long)ldc + gn] = v;
                }
            }
        }
    }
}

// ---------------- launch ----------------

extern "C" void kernel_launch(void* const* d_in, const int* in_sizes, int n_in,
                              void* d_out, int out_size, void* d_ws, size_t ws_size,
                              hipStream_t stream) {
    (void)in_sizes; (void)n_in; (void)out_size;
    const float* x   = (const float*)d_in[0];
    const float* rw1 = (const float*)d_in[1];
    const float* rb1 = (const float*)d_in[2];
    const float* rw2 = (const float*)d_in[3];
    const float* rb2 = (const float*)d_in[4];
    const float* ew1 = (const float*)d_in[5];
    const float* eb1 = (const float*)d_in[6];
    const float* ew2 = (const float*)d_in[7];
    const float* eb2 = (const float*)d_in[8];

    const bool dbuf = ws_size >= 69206016u;   // double-buffered weights (prep overlap)

    char* ws = (char*)d_ws;
    unsigned short* xb   = (unsigned short*)(ws);                 // 16,777,216 B
    float*          wbuf = (float*)         (ws + 16777216);      //    262,144 B
    unsigned short* Hb   = (unsigned short*)(ws + 17039360);      // 34,603,008 B
    size_t off = 51642368;
    unsigned short* rw1tb[2];
    unsigned short* W1tb[2];
    unsigned short* W2tb[2];
    rw1tb[0] = (unsigned short*)(ws + off);
    rw1tb[1] = dbuf ? (unsigned short*)(ws + off + 262144) : rw1tb[0];
    off += (dbuf ? 2u : 1u) * 262144u;
    W1tb[0] = (unsigned short*)(ws + off);
    W1tb[1] = dbuf ? (unsigned short*)(ws + off + 4194304) : W1tb[0];
    off += (dbuf ? 2u : 1u) * 4194304u;
    W2tb[0] = (unsigned short*)(ws + off);
    W2tb[1] = dbuf ? (unsigned short*)(ws + off + 4325376) : W2tb[0];

    mega0<<<3124, 512, 0, stream>>>(x, xb, Hb, rw1, ew1, ew2, eb2,
                                    rw1tb[0], W1tb[0], W2tb[0]);

    for (int l = 0; l < 3; ++l) {
        const int b  = dbuf ? (l & 1) : 0;
        const int nb = dbuf ? (b ^ 1) : 0;
        const int ln = (l + 1 < 3) ? (l + 1) : 0;   // next-level srcs (unused when grid=128)

        if (!dbuf && l > 0)
            prep_lvl512<<<1060, 512, 0, stream>>>(rw1 + (size_t)l * DD * RHH,
                                                  ew1 + (size_t)l * EE * DD * EHH,
                                                  ew2 + (size_t)l * EE * EHH * DD,
                                                  eb2 + (size_t)l * EE * DD,
                                                  rw1tb[0], W1tb[0], W2tb[0]);

        const int rp_grid = (dbuf && l < 2) ? 1188 : 128;
        router_prep<<<rp_grid, 512, 0, stream>>>(
            xb, rw1tb[b],
            rw2 + (size_t)l * RHH * EE, rb1 + (size_t)l * RHH, rb2 + (size_t)l * EE,
            wbuf, Hb,
            rw1 + (size_t)ln * DD * RHH, ew1 + (size_t)ln * EE * DD * EHH,
            ew2 + (size_t)ln * EE * EHH * DD, eb2 + (size_t)ln * EE * DD,
            rw1tb[nb], W1tb[nb], W2tb[nb]);

        // H' = relu(x @ W1 + b1) * w   [8192, 2048] (stride KX)
        gemmT<256, 32, 4, 4, 1><<<dim3(32, 8), 512, 0, stream>>>(
            xb, W1tb[b], Hb, eb1 + (size_t)l * NE1, wbuf, DD, DD, DD, KX);

        // out = H' @ W2ext (bias folded via K-extension)
        if (l < 2)
            gemmT<128, 64, 3, 2, 2><<<dim3(32, 8), 512, 0, stream>>>(
                Hb, W2tb[b], xb, nullptr, nullptr, KX, KX, KX, DD);
        else
            gemmT<128, 64, 3, 2, 3><<<dim3(32, 8), 512, 0, stream>>>(
                Hb, W2tb[b], d_out, nullptr, nullptr, KX, KX, KX, DD);
    }
}